// Round 1
// baseline (320.340 us; speedup 1.0000x reference)
//
#include <hip/hip_runtime.h>
#include <hip/hip_cooperative_groups.h>

namespace cg = cooperative_groups;

constexpr int Bn = 8;
constexpr int Ln = 4096;
constexpr int Dn = 768;
constexpr int D4 = Dn / 4;              // 192 float4 columns
constexpr int THREADS = 384;            // 6 waves/block
constexpr int CHUNKS_TOT = 512;         // 64-row chunks over all B*L rows
constexpr int RPC = (Bn * Ln) / CHUNKS_TOT;   // 64 rows per chunk
constexpr int CPB = CHUNKS_TOT / Bn;    // 64 chunks per batch

// ---------------------------------------------------------------------------
// Single cooperative kernel, 3 phases, 2 grid syncs.
//   P1: partial column sums per 64-row chunk  (HBM-bound: read x once)
//   P2: fold 64 partials/batch -> colsum -> m[b,d] = colsum * ||colsum||^2/(L^4 D^2)
//   P3: out[b,l,d] = alpha[l] + (x_row . m_b) * x[b,l,d]   (read x again + write out)
// Fusing kills 2 inter-dispatch gaps and hides K2's 8-CU latency inside the
// resident grid. Grid-stride everywhere so any co-resident grid size works.
// ---------------------------------------------------------------------------
__global__ __launch_bounds__(THREADS, 3)
void k_all(const float* __restrict__ x, const float* __restrict__ alpha,
           float* __restrict__ out, float* __restrict__ part,
           float* __restrict__ m) {
    cg::grid_group grid = cg::this_grid();
    const int t    = threadIdx.x;
    const int h    = t / 192;            // half: rows 0..31 vs 32..63
    const int col  = t % 192;            // float4 column
    __shared__ float4 buf[D4];           // half-combine scratch (3 KB)
    __shared__ float  wsum[3];

    const float4* x4    = (const float4*)x;
    float4*       part4 = (float4*)part;
    float4*       m4    = (float4*)m;

    // ---------------- Phase 1: per-chunk partial column sums ----------------
    for (int ch = blockIdx.x; ch < CHUNKS_TOT; ch += gridDim.x) {
        const float4* p = x4 + ((size_t)ch * RPC + h * 32) * D4 + col;
        float4 s = {0.f, 0.f, 0.f, 0.f};
        #pragma unroll 4
        for (int l = 0; l < 32; ++l) {
            float4 v = p[(size_t)l * D4];
            s.x += v.x; s.y += v.y; s.z += v.z; s.w += v.w;
        }
        __syncthreads();                 // buf reuse across ch iterations
        if (h == 1) buf[col] = s;
        __syncthreads();
        if (h == 0) {
            float4 o = buf[col];
            s.x += o.x; s.y += o.y; s.z += o.z; s.w += o.w;
            part4[(size_t)ch * D4 + col] = s;
        }
    }

    grid.sync();

    // ------- Phase 2: fold partials per batch, scale -> m (8 blocks) -------
    for (int b = blockIdx.x; b < Bn; b += gridDim.x) {
        const float4* pb = part4 + (size_t)b * CPB * D4;
        float4 s = {0.f, 0.f, 0.f, 0.f};
        for (int c = h * 32; c < h * 32 + 32; ++c) {
            float4 v = pb[(size_t)c * D4 + col];
            s.x += v.x; s.y += v.y; s.z += v.z; s.w += v.w;
        }
        if (h == 1) buf[col] = s;
        __syncthreads();
        float4 cs = {0.f, 0.f, 0.f, 0.f};
        if (h == 0) {
            float4 o = buf[col];
            cs.x = s.x + o.x; cs.y = s.y + o.y;
            cs.z = s.z + o.z; cs.w = s.w + o.w;
            float ssq = cs.x * cs.x + cs.y * cs.y + cs.z * cs.z + cs.w * cs.w;
            #pragma unroll
            for (int off = 1; off < 64; off <<= 1) ssq += __shfl_xor(ssq, off);
            if ((t & 63) == 0) wsum[t >> 6] = ssq;
        }
        __syncthreads();
        if (h == 0) {
            float ss = wsum[0] + wsum[1] + wsum[2];
            const float f1 = 1.0f / ((float)Ln * (float)Dn);       // 1/(L*D)
            float scale = ss * f1 * f1 / ((float)Ln * (float)Ln);  // ||cs||^2/(L^4 D^2)
            float4 mv = {cs.x * scale, cs.y * scale, cs.z * scale, cs.w * scale};
            m4[(size_t)b * D4 + col] = mv;
        }
        __syncthreads();
    }

    grid.sync();

    // ------------- Phase 3: fused row-dot + epilogue (as K3) ---------------
    const int wave = t >> 6, lane = t & 63;      // 6 waves/block
    for (int ch = blockIdx.x; ch < CHUNKS_TOT; ch += gridDim.x) {
        const int row0 = ch * RPC;
        const float4* mr = m4 + (size_t)(row0 >> 12) * D4;
        float4 m0 = mr[lane], m1 = mr[lane + 64], m2 = mr[lane + 128];
        for (int r = wave; r < RPC; r += 6) {
            const int row = row0 + r;
            const float4* xr = x4 + (size_t)row * D4;
            float4 x0 = xr[lane], x1 = xr[lane + 64], x2 = xr[lane + 128];
            float acc = x0.x * m0.x + x0.y * m0.y + x0.z * m0.z + x0.w * m0.w
                      + x1.x * m1.x + x1.y * m1.y + x1.z * m1.z + x1.w * m1.w
                      + x2.x * m2.x + x2.y * m2.y + x2.z * m2.z + x2.w * m2.w;
            #pragma unroll
            for (int off = 1; off < 64; off <<= 1) acc += __shfl_xor(acc, off);
            float a = alpha[row & (Ln - 1)];
            float4* orow = (float4*)out + (size_t)row * D4;
            float4 o0 = {a + acc * x0.x, a + acc * x0.y, a + acc * x0.z, a + acc * x0.w};
            float4 o1 = {a + acc * x1.x, a + acc * x1.y, a + acc * x1.z, a + acc * x1.w};
            float4 o2 = {a + acc * x2.x, a + acc * x2.y, a + acc * x2.z, a + acc * x2.w};
            orow[lane]       = o0;
            orow[lane + 64]  = o1;
            orow[lane + 128] = o2;
        }
    }
}

// ---------------------------------------------------------------------------
extern "C" void kernel_launch(void* const* d_in, const int* in_sizes, int n_in,
                              void* d_out, int out_size, void* d_ws, size_t ws_size,
                              hipStream_t stream) {
    const float* x     = (const float*)d_in[0];   // [B, L, D]
    const float* alpha = (const float*)d_in[1];   // [L, 1]
    float* out  = (float*)d_out;                  // [B, L, D]

    // ws layout: part[CHUNKS_TOT*D] | m[B*D]  (~1.6 MB, same as before)
    float* part = (float*)d_ws;
    float* m    = part + (size_t)CHUNKS_TOT * Dn;

    // Co-resident grid size (cooperative launch requires it). launch_bounds
    // guarantees >=2 blocks/CU (384 thr, ~3 KB LDS), i.e. grid 512 fits.
    static int grid = 0;
    if (grid == 0) {
        int occ = 0;
        if (hipOccupancyMaxActiveBlocksPerMultiprocessor(
                &occ, reinterpret_cast<const void*>(k_all), THREADS, 0) != hipSuccess ||
            occ < 1)
            occ = 1;
        grid = occ * 256;                 // 256 CUs on MI355X
        if (grid > CHUNKS_TOT) grid = CHUNKS_TOT;
    }

    void* args[] = {(void*)&x, (void*)&alpha, (void*)&out, (void*)&part, (void*)&m};
    hipLaunchCooperativeKernel(reinterpret_cast<const void*>(k_all),
                               dim3(grid), dim3(THREADS), args, 0u, stream);
}

// Round 3
// 196.391 us; speedup vs baseline: 1.6311x; 1.6311x over previous
//
#include <hip/hip_runtime.h>

constexpr int Bn = 8;
constexpr int Ln = 4096;
constexpr int Dn = 768;
constexpr int D4 = Dn / 4;               // 192 float4 columns
constexpr int CPB = 128;                 // chunks per batch
constexpr int CHUNKS_TOT = Bn * CPB;     // 1024 blocks in K1
constexpr int RPC = Ln / CPB;            // 32 rows per chunk

typedef float vfloat4 __attribute__((ext_vector_type(4)));  // clang-native vec4

// ---------------------------------------------------------------------------
// K1: partial column sums (no atomics). grid = 1024 x 192.
// Thread t owns float4-column t; 32 rows per chunk; 4 blocks/CU (12 waves/CU),
// 8 independent 1KB-coalesced wave-loads in flight -> HBM-bound.
// part[ch][d] = sum over the chunk's 32 rows (chunk ch belongs to batch ch/128).
// ---------------------------------------------------------------------------
__global__ __launch_bounds__(192)
void k_colsum_part(const float4* __restrict__ x, float4* __restrict__ part) {
    const int ch = blockIdx.x;
    const int t  = threadIdx.x;          // 0..191
    const float4* p = x + (size_t)ch * RPC * D4 + t;
    float4 s = {0.f, 0.f, 0.f, 0.f};
    #pragma unroll 8
    for (int l = 0; l < RPC; ++l) {
        float4 v = p[(size_t)l * D4];
        s.x += v.x; s.y += v.y; s.z += v.z; s.w += v.w;
    }
    part[(size_t)ch * D4 + t] = s;
}

// ---------------------------------------------------------------------------
// K2: fold 128 partials/batch -> colsum[b][d]. grid = 8*12 = 96 blocks x 64.
// Each block reads 32 KB (vs 196 KB/CU in the old 8-block version) -> ~3 us.
// Scale/ssq is NOT computed here; K3 derives it per-wave from colsum.
// ---------------------------------------------------------------------------
__global__ __launch_bounds__(64)
void k_colsum_fold(const float* __restrict__ part, float* __restrict__ colsum) {
    const int b    = blockIdx.x / 12;
    const int sl   = blockIdx.x % 12;    // 64-float slice of D
    const int lane = threadIdx.x;        // 0..63
    const float* pb = part + (size_t)b * CPB * Dn + sl * 64 + lane;
    float s = 0.f;
    #pragma unroll 8
    for (int c = 0; c < CPB; ++c) s += pb[(size_t)c * Dn];
    colsum[b * Dn + sl * 64 + lane] = s;
}

// ---------------------------------------------------------------------------
// K3: fused ssq + rowdot + epilogue. One wave per row, no LDS, no syncthreads.
// Each wave redundantly computes ssq = ||colsum_b||^2 from 3 L2-hot float4
// loads (12 FMA + 6 shuffles, fully hidden), then:
//   coef = (x_row . colsum_b) * ssq / (L^4 D^2)
//   out[b,l,d] = alpha[l] + coef * x[b,l,d]
// x reads hit L3 (resident from K1); out stores are nontemporal.
// ---------------------------------------------------------------------------
__global__ __launch_bounds__(256)
void k_fused(const float4* __restrict__ x, const float4* __restrict__ colsum,
             const float* __restrict__ alpha, vfloat4* __restrict__ out) {
    const int wave = threadIdx.x >> 6;
    const int lane = threadIdx.x & 63;
    const int row  = blockIdx.x * 4 + wave;   // [0, B*L)
    const int b    = row >> 12;
    const int l    = row & (Ln - 1);

    const float4* cs = colsum + (size_t)b * D4;
    float4 c0 = cs[lane], c1 = cs[lane + 64], c2 = cs[lane + 128];

    float ssq = c0.x * c0.x + c0.y * c0.y + c0.z * c0.z + c0.w * c0.w
              + c1.x * c1.x + c1.y * c1.y + c1.z * c1.z + c1.w * c1.w
              + c2.x * c2.x + c2.y * c2.y + c2.z * c2.z + c2.w * c2.w;
    #pragma unroll
    for (int off = 1; off < 64; off <<= 1) ssq += __shfl_xor(ssq, off);

    const float4* xr = x + (size_t)row * D4;
    float4 x0 = xr[lane], x1 = xr[lane + 64], x2 = xr[lane + 128];

    float acc = x0.x * c0.x + x0.y * c0.y + x0.z * c0.z + x0.w * c0.w
              + x1.x * c1.x + x1.y * c1.y + x1.z * c1.z + x1.w * c1.w
              + x2.x * c2.x + x2.y * c2.y + x2.z * c2.z + x2.w * c2.w;
    #pragma unroll
    for (int off = 1; off < 64; off <<= 1) acc += __shfl_xor(acc, off);

    const float f1 = 1.0f / ((float)Ln * (float)Dn);              // 1/(L*D)
    const float k  = ssq * f1 * f1 / ((float)Ln * (float)Ln);     // ssq/(L^4 D^2)
    const float coef = acc * k;

    const float a = alpha[l];
    vfloat4* orow = out + (size_t)row * D4;
    vfloat4 o0 = {a + coef * x0.x, a + coef * x0.y, a + coef * x0.z, a + coef * x0.w};
    vfloat4 o1 = {a + coef * x1.x, a + coef * x1.y, a + coef * x1.z, a + coef * x1.w};
    vfloat4 o2 = {a + coef * x2.x, a + coef * x2.y, a + coef * x2.z, a + coef * x2.w};
    __builtin_nontemporal_store(o0, &orow[lane]);
    __builtin_nontemporal_store(o1, &orow[lane + 64]);
    __builtin_nontemporal_store(o2, &orow[lane + 128]);
}

// ---------------------------------------------------------------------------
extern "C" void kernel_launch(void* const* d_in, const int* in_sizes, int n_in,
                              void* d_out, int out_size, void* d_ws, size_t ws_size,
                              hipStream_t stream) {
    const float* x     = (const float*)d_in[0];   // [B, L, D]
    const float* alpha = (const float*)d_in[1];   // [L, 1]
    float* out = (float*)d_out;                   // [B, L, D]

    // ws layout: part[1024*768] (3 MB) | colsum[8*768] (24 KB)
    float* part   = (float*)d_ws;
    float* colsum = part + (size_t)CHUNKS_TOT * Dn;

    k_colsum_part<<<CHUNKS_TOT, 192, 0, stream>>>((const float4*)x, (float4*)part);
    k_colsum_fold<<<Bn * 12, 64, 0, stream>>>(part, colsum);
    k_fused<<<(Bn * Ln) / 4, 256, 0, stream>>>((const float4*)x, (const float4*)colsum,
                                               alpha, (vfloat4*)out);
}